// Round 8
// baseline (304.607 us; speedup 1.0000x reference)
//
#include <hip/hip_runtime.h>
#include <math.h>

#define BATCH 4
#define TSEQ  2048
#define CEMB  1024
#define NHEAD 16
#define HD    64
#define MROWS (BATCH * TSEQ)   // 8192
#define QSCALE 11.5415603271f  // 8 * log2(e): softmax runs in exp2 domain

typedef _Float16 half8 __attribute__((ext_vector_type(8)));
typedef _Float16 half4 __attribute__((ext_vector_type(4)));
typedef float    floatx4 __attribute__((ext_vector_type(4)));

#define GLOBAL_AS __attribute__((address_space(1)))
#define LDS_AS    __attribute__((address_space(3)))

__device__ __forceinline__ void lds_dma16(const _Float16* g, _Float16* l) {
    __builtin_amdgcn_global_load_lds((const GLOBAL_AS unsigned int*)g,
                                     (LDS_AS unsigned int*)l, 16, 0, 0);
}

// raw v_exp_f32 (2^x). VALU interlocks handle the hazard; exp2(-inf)=0.
__device__ __forceinline__ float fast_exp2(float x) {
    float r; asm("v_exp_f32 %0, %1" : "=v"(r) : "v"(x)); return r;
}

// ---------------------------------------------------------------------------
// Kernel 0: fp32 -> fp16 convert prepass (float4 -> half4)
// ---------------------------------------------------------------------------
__global__ __launch_bounds__(256)
void cvt_fp16(const float* __restrict__ x, const float* __restrict__ wa,
              const float* __restrict__ wp, _Float16* __restrict__ x16,
              _Float16* __restrict__ wa16, _Float16* __restrict__ wp16)
{
    const int n1 = (BATCH * TSEQ * CEMB) / 4;
    const int n2 = (3 * CEMB * CEMB) / 4;
    int i = blockIdx.x * 256 + threadIdx.x;
    const float* src; _Float16* dst; int j;
    if (i < n1)            { src = x;  dst = x16;  j = i; }
    else if (i < n1 + n2)  { src = wa; dst = wa16; j = i - n1; }
    else                   { src = wp; dst = wp16; j = i - n1 - n2; }
    float4 v = ((const float4*)src)[j];
    half4 h = { (_Float16)v.x, (_Float16)v.y, (_Float16)v.z, (_Float16)v.w };
    ((half4*)dst)[j] = h;
}

// ---------------------------------------------------------------------------
// GEMM staging: 128x32 fp16 tile, DMA, XOR swizzle c = pc ^ (row&3).
// ---------------------------------------------------------------------------
__device__ __forceinline__ void stage32(const _Float16* __restrict__ gbase,
                                        _Float16* __restrict__ lds,
                                        int row0, int kk, int tid)
{
#pragma unroll
    for (int p = 0; p < 2; ++p) {
        int ci  = p * 256 + tid;
        int row = ci >> 2, pcc = ci & 3;
        int c   = pcc ^ (row & 3);
        lds_dma16(gbase + (size_t)(row0 + row) * CEMB + kk + c * 8, lds + ci * 8);
    }
}

// ---------------------------------------------------------------------------
// Kernel 1: qkv = x16 @ Wa16^T. 1-D grid with XCD-aware decode: each XCD owns
// 3 N-panels (768 KB of Wa16, L2-resident, 64 reuses) x all M-panels.
// Epilogue stages C through LDS for coalesced half8 stores; v transposed.
// q pre-scaled by 8*log2e.
// ---------------------------------------------------------------------------
__global__ __launch_bounds__(256)
void qkv_gemm(const _Float16* __restrict__ A, const _Float16* __restrict__ B,
              _Float16* __restrict__ q16, _Float16* __restrict__ k16,
              _Float16* __restrict__ v16)
{
    __shared__ __align__(16) _Float16 smem[16384];   // 32 KB: dbuf tiles / C-tile
    const int tid = threadIdx.x, lane = tid & 63, wave = tid >> 6;
    const int wm = wave & 1, wn = wave >> 1;
    // XCD-aware decode: 1536 blocks; xcd = bid&7 owns bx in {3*xcd..3*xcd+2}
    const int bid = blockIdx.x;
    const int xcd = bid & 7, w = bid >> 3;           // w in 0..191
    const int bx = xcd * 3 + (w >> 6);               // 0..23 (N-tile)
    const int by = w & 63;                           // 0..63 (M-tile)
    const int m0 = by * 128, n0 = bx * 128;
    const int l15 = lane & 15, quad = lane >> 4;

    floatx4 acc[4][4];
#pragma unroll
    for (int i = 0; i < 4; ++i)
#pragma unroll
        for (int j = 0; j < 4; ++j) acc[i][j] = (floatx4){0.f, 0.f, 0.f, 0.f};

    stage32(A, smem, m0, 0, tid);
    stage32(B, smem + 8192, n0, 0, tid);
    for (int kt = 0; kt < 32; ++kt) {
        const int cur = kt & 1;
        _Float16* Asc = smem + cur * 4096;
        _Float16* Bsc = smem + 8192 + cur * 4096;
        __syncthreads();                      // drains DMA(kt)
        if (kt < 31) {
            stage32(A, smem + (cur ^ 1) * 4096, m0, (kt + 1) * 32, tid);
            stage32(B, smem + 8192 + (cur ^ 1) * 4096, n0, (kt + 1) * 32, tid);
        }
        half8 af[4], bf[4];
#pragma unroll
        for (int mt = 0; mt < 4; ++mt) {
            int row = wm * 64 + mt * 16 + l15;
            af[mt] = *(const half8*)(Asc + row * 32 + (quad ^ (row & 3)) * 8);
        }
#pragma unroll
        for (int nt = 0; nt < 4; ++nt) {
            int row = wn * 64 + nt * 16 + l15;
            bf[nt] = *(const half8*)(Bsc + row * 32 + (quad ^ (row & 3)) * 8);
        }
#pragma unroll
        for (int mt = 0; mt < 4; ++mt)
#pragma unroll
            for (int nt = 0; nt < 4; ++nt)
                acc[mt][nt] = __builtin_amdgcn_mfma_f32_16x16x32_f16(af[mt], bf[nt], acc[mt][nt], 0, 0, 0);
    }

    __syncthreads();                          // all frag reads done; reuse smem
    const int rbase = quad << 2;
    if (n0 < 2 * CEMB) {
        // --- q/k: C[t][n'] with chunk swizzle pc = (n>>3) ^ (t&15) ---
        const float scale = (n0 < CEMB) ? QSCALE : 1.0f;
#pragma unroll
        for (int mt = 0; mt < 4; ++mt)
#pragma unroll
            for (int nt = 0; nt < 4; ++nt)
#pragma unroll
                for (int r = 0; r < 4; ++r) {
                    int t = wm * 64 + mt * 16 + rbase + r;
                    int n = wn * 64 + nt * 16 + l15;
                    int pc = (n >> 3) ^ (t & 15);
                    smem[t * 128 + pc * 8 + (n & 7)] = (_Float16)(acc[mt][nt][r] * scale);
                }
        __syncthreads();
        const int chunk = tid & 7;
#pragma unroll
        for (int i = 0; i < 8; ++i) {
            int gr = (tid >> 3) + i * 32;     // 0..255: (seg,t)
            int seg = gr >> 7, t = gr & 127;
            int pc = (seg * 8 + chunk) ^ (t & 15);
            half8 v = *(const half8*)(smem + t * 128 + pc * 8);
            int gm = m0 + t, b = gm >> 11, tt = gm & (TSEQ - 1);
            int gnb = n0 + seg * 64;
            _Float16* dst;
            if (n0 < CEMB) {
                int h = gnb >> 6;
                dst = q16 + (((size_t)(b * NHEAD + h)) * TSEQ + tt) * HD;
            } else {
                int h = (gnb - CEMB) >> 6;
                dst = k16 + (((size_t)(b * NHEAD + h)) * TSEQ + tt) * HD;
            }
            *(half8*)(dst + chunk * 8) = v;
        }
    } else {
        // --- v: transpose in LDS: C[n'][t] with pc = (t>>3) ^ (n&15) ---
#pragma unroll
        for (int mt = 0; mt < 4; ++mt)
#pragma unroll
            for (int nt = 0; nt < 4; ++nt)
#pragma unroll
                for (int r = 0; r < 4; ++r) {
                    int t = wm * 64 + mt * 16 + rbase + r;
                    int n = wn * 64 + nt * 16 + l15;
                    int pc = (t >> 3) ^ (n & 15);
                    smem[n * 128 + pc * 8 + (t & 7)] = (_Float16)acc[mt][nt][r];
                }
        __syncthreads();
        const int chunk = tid & 15;           // 16 chunks of 8 along t
        const int b = m0 >> 11, tblk = m0 & (TSEQ - 1);
#pragma unroll
        for (int i = 0; i < 8; ++i) {
            int row = (tid >> 4) + i * 16;    // n' 0..127
            int pc = chunk ^ (row & 15);
            half8 v = *(const half8*)(smem + row * 128 + pc * 8);
            int c2 = n0 - 2 * CEMB + row;
            int h = c2 >> 6, d = c2 & 63;
            *(half8*)(v16 + (((size_t)(b * NHEAD + h)) * HD + d) * TSEQ + tblk + chunk * 8) = v;
        }
    }
}

// ---------------------------------------------------------------------------
// Kernel 2: flash attention. S^T = K·Q^T; P stays in registers in B-layout
// for mfma_16x16x16f16 (O^T = V^T·P^T). UNPAIRED: 2048 single-q-tile blocks,
// oversubscribed (8/CU asked, 5 resident) so backfill balances causal skew.
// XCD-aware decode keeps each XCD's K/V panels L2-resident.
// ---------------------------------------------------------------------------
__device__ __forceinline__ void attn_tile(
    const half8& qf0, const half8& qf1,
    float& m_i, float& l_i, floatx4 (&o)[4],
    const _Float16* __restrict__ Ks, const _Float16* __restrict__ Vs,
    bool domask, int l15, int quad, int relq)
{
    floatx4 s[4];
#pragma unroll
    for (int nt = 0; nt < 4; ++nt) {
        int row = nt * 16 + l15;
        int pc0 = quad ^ (row & 7);
        half8 kf0 = *(const half8*)(Ks + row * 64 + pc0 * 8);
        half8 kf1 = *(const half8*)(Ks + row * 64 + (pc0 ^ 4) * 8);
        floatx4 z = (floatx4){0.f, 0.f, 0.f, 0.f};
        z = __builtin_amdgcn_mfma_f32_16x16x32_f16(kf0, qf0, z, 0, 0, 0);
        z = __builtin_amdgcn_mfma_f32_16x16x32_f16(kf1, qf1, z, 0, 0, 0);
        s[nt] = z;   // S^T[key = nt*16+quad*4+r][q = l15], exp2-domain logits
    }
    if (domask) {
#pragma unroll
        for (int nt = 0; nt < 4; ++nt)
#pragma unroll
            for (int r = 0; r < 4; ++r)
                if (nt * 16 + quad * 4 + r > relq) s[nt][r] = -INFINITY;
    }
    float mx = m_i;
#pragma unroll
    for (int nt = 0; nt < 4; ++nt)
        mx = fmaxf(mx, fmaxf(fmaxf(s[nt][0], s[nt][1]), fmaxf(s[nt][2], s[nt][3])));
    mx = fmaxf(mx, __shfl_xor(mx, 16, 64));
    mx = fmaxf(mx, __shfl_xor(mx, 32, 64));
    float alpha = fast_exp2(m_i - mx);
    m_i = mx;
    float rs = 0.f;
    half4 p[4];
#pragma unroll
    for (int nt = 0; nt < 4; ++nt) {
        float p0 = fast_exp2(s[nt][0] - mx), p1 = fast_exp2(s[nt][1] - mx);
        float p2 = fast_exp2(s[nt][2] - mx), p3 = fast_exp2(s[nt][3] - mx);
        rs += (p0 + p1) + (p2 + p3);
        p[nt] = (half4){ (_Float16)p0, (_Float16)p1, (_Float16)p2, (_Float16)p3 };
    }
    rs += __shfl_xor(rs, 16, 64);
    rs += __shfl_xor(rs, 32, 64);
    l_i = l_i * alpha + rs;
#pragma unroll
    for (int mt = 0; mt < 4; ++mt)
#pragma unroll
        for (int r = 0; r < 4; ++r) o[mt][r] *= alpha;
#pragma unroll
    for (int mt = 0; mt < 4; ++mt) {
        int d = mt * 16 + l15;
#pragma unroll
        for (int nt = 0; nt < 4; ++nt) {
            int pc = (2 * nt + (quad >> 1)) ^ (d & 7);
            half4 vf = *(const half4*)(Vs + d * 64 + pc * 8 + (quad & 1) * 4);
            o[mt] = __builtin_amdgcn_mfma_f32_16x16x16f16(vf, p[nt], o[mt], 0, 0, 0);
        }
    }
}

__global__ __launch_bounds__(256)
void attn_fwd(const _Float16* __restrict__ q16, const _Float16* __restrict__ k16,
              const _Float16* __restrict__ v16, _Float16* __restrict__ o16)
{
    __shared__ __align__(16) _Float16 Ks[2][64 * 64];
    __shared__ __align__(16) _Float16 Vs[2][64 * 64];
    const int tid = threadIdx.x, lane = tid & 63, wave = tid >> 6;
    const int l15 = lane & 15, quad = lane >> 4;
    // XCD-aware decode: 2048 blocks; xcd = bid&7 owns bh in {8*xcd..8*xcd+7}
    const int bid = blockIdx.x;
    const int xcd = bid & 7, w = bid >> 3;           // w in 0..255
    const int bh = xcd * 8 + (w >> 5);               // 0..63
    const int qt = w & 31;                           // 0..31
    const int b = bh >> 4, h = bh & 15;
    const int q0 = qt * 64;
    const _Float16* qp = q16 + (size_t)bh * TSEQ * HD;
    const _Float16* kp = k16 + (size_t)bh * TSEQ * HD;
    const _Float16* vp = v16 + (size_t)bh * HD * TSEQ;

    const int relq = wave * 16 + l15;
    half8 q0f = *(const half8*)(qp + (size_t)(q0 + relq) * HD + quad * 8);
    half8 q1f = *(const half8*)(qp + (size_t)(q0 + relq) * HD + 32 + quad * 8);

    float m_i = -INFINITY, l_i = 0.f;
    floatx4 o[4];
#pragma unroll
    for (int mt = 0; mt < 4; ++mt) o[mt] = (floatx4){0.f,0.f,0.f,0.f};

#define STAGE_KV(kt0, buf)                                                     \
    {                                                                          \
        _Float16* kd = Ks[buf];                                                \
        _Float16* vd = Vs[buf];                                                \
        _Pragma("unroll")                                                      \
        for (int p = 0; p < 2; ++p) {                                          \
            int ci = p * 256 + tid;                                            \
            int row = ci >> 3;                                                 \
            int c = (ci & 7) ^ (row & 7);                                      \
            lds_dma16(kp + (size_t)((kt0) + row) * HD + c * 8, kd + ci * 8);   \
            lds_dma16(vp + (size_t)row * TSEQ + (kt0) + c * 8, vd + ci * 8);   \
        }                                                                      \
    }

    STAGE_KV(0, 0);
    for (int kt = 0; kt <= qt; ++kt) {
        const int cur = kt & 1;
        __syncthreads();                       // drains DMA(kt) into buf[cur]
        if (kt < qt) STAGE_KV((kt + 1) * 64, cur ^ 1);
        attn_tile(q0f, q1f, m_i, l_i, o, Ks[cur], Vs[cur], (kt == qt), l15, quad, relq);
    }
#undef STAGE_KV

    const float inv = 1.f / l_i;
    const size_t base = ((size_t)(b * TSEQ + q0 + relq)) * CEMB + h * HD + quad * 4;
#pragma unroll
    for (int mt = 0; mt < 4; ++mt) {
        half4 hv = { (_Float16)(o[mt][0] * inv), (_Float16)(o[mt][1] * inv),
                     (_Float16)(o[mt][2] * inv), (_Float16)(o[mt][3] * inv) };
        *(half4*)(o16 + base + mt * 16) = hv;
    }
}

// ---------------------------------------------------------------------------
// Kernel 3: y = attn16 @ Wp16^T + b_proj, fp32 out. 64x128 tile -> 1024
// blocks (4/CU); gridDim.x=8 naturally maps one N-panel per XCD.
// ---------------------------------------------------------------------------
__global__ __launch_bounds__(256)
void proj_gemm(const _Float16* __restrict__ A, const _Float16* __restrict__ B,
               const float* __restrict__ bias, float* __restrict__ out)
{
    __shared__ __align__(16) _Float16 As2[2][64 * 32];
    __shared__ __align__(16) _Float16 Bs2[2][128 * 32];
    const int tid = threadIdx.x, lane = tid & 63, wave = tid >> 6;
    const int wm = wave & 1, wn = wave >> 1;
    const int m0 = blockIdx.y * 64, n0 = blockIdx.x * 128;
    const int l15 = lane & 15, quad = lane >> 4;

    floatx4 acc[2][4];
#pragma unroll
    for (int i = 0; i < 2; ++i)
#pragma unroll
        for (int j = 0; j < 4; ++j) acc[i][j] = (floatx4){0.f, 0.f, 0.f, 0.f};

#define STAGE_A(kk, buf)                                                       \
    {                                                                          \
        int row = tid >> 2, c = (tid & 3) ^ (row & 3);                         \
        lds_dma16(A + (size_t)(m0 + row) * CEMB + (kk) + c * 8,                \
                  As2[buf] + tid * 8);                                         \
    }

    STAGE_A(0, 0);
    stage32(B, Bs2[0], n0, 0, tid);
    for (int kt = 0; kt < 32; ++kt) {
        const int cur = kt & 1;
        __syncthreads();
        if (kt < 31) {
            STAGE_A((kt + 1) * 32, cur ^ 1);
            stage32(B, Bs2[cur ^ 1], n0, (kt + 1) * 32, tid);
        }
        half8 af[2], bf[4];
#pragma unroll
        for (int mt = 0; mt < 2; ++mt) {
            int row = wm * 32 + mt * 16 + l15;
            af[mt] = *(const half8*)(As2[cur] + row * 32 + (quad ^ (row & 3)) * 8);
        }
#pragma unroll
        for (int nt = 0; nt < 4; ++nt) {
            int row = wn * 64 + nt * 16 + l15;
            bf[nt] = *(const half8*)(Bs2[cur] + row * 32 + (quad ^ (row & 3)) * 8);
        }
#pragma unroll
        for (int mt = 0; mt < 2; ++mt)
#pragma unroll
            for (int nt = 0; nt < 4; ++nt)
                acc[mt][nt] = __builtin_amdgcn_mfma_f32_16x16x32_f16(af[mt], bf[nt], acc[mt][nt], 0, 0, 0);
    }
#undef STAGE_A

    const int rbase = quad << 2;
#pragma unroll
    for (int mt = 0; mt < 2; ++mt)
#pragma unroll
        for (int nt = 0; nt < 4; ++nt) {
            int gn = n0 + wn * 64 + nt * 16 + l15;
            float bb = bias[gn];
#pragma unroll
            for (int r = 0; r < 4; ++r) {
                int gm = m0 + wm * 32 + mt * 16 + rbase + r;
                out[(size_t)gm * CEMB + gn] = acc[mt][nt][r] + bb;
            }
        }
}

// ---------------------------------------------------------------------------
extern "C" void kernel_launch(void* const* d_in, const int* in_sizes, int n_in,
                              void* d_out, int out_size, void* d_ws, size_t ws_size,
                              hipStream_t stream) {
    const float* x     = (const float*)d_in[0];
    const float* Wattn = (const float*)d_in[1];
    const float* Wproj = (const float*)d_in[2];
    const float* bproj = (const float*)d_in[3];
    float* out = (float*)d_out;

    const size_t nx  = (size_t)BATCH * TSEQ * CEMB;
    const size_t nwa = (size_t)3 * CEMB * CEMB;
    const size_t nwp = (size_t)CEMB * CEMB;
    const size_t per = (size_t)BATCH * NHEAD * TSEQ * HD;

    _Float16* x16    = (_Float16*)d_ws;
    _Float16* wa16   = x16 + nx;
    _Float16* wp16   = wa16 + nwa;
    _Float16* q16    = wp16 + nwp;
    _Float16* k16    = q16 + per;
    _Float16* v16    = k16 + per;
    _Float16* attn16 = x16;   // alias: x16 fully consumed before attn writes

    const int nconv = (int)((nx + nwa + nwp) / 4);
    cvt_fp16<<<nconv / 256, 256, 0, stream>>>(x, Wattn, Wproj, x16, wa16, wp16);
    qkv_gemm<<<1536, 256, 0, stream>>>(x16, wa16, q16, k16, v16);
    attn_fwd<<<2048, 256, 0, stream>>>(q16, k16, v16, attn16);
    proj_gemm<<<dim3(CEMB / 128, MROWS / 64), 256, 0, stream>>>(attn16, wp16, bproj, out);
}